// Round 2
// baseline (119.311 us; speedup 1.0000x reference)
//
#include <hip/hip_runtime.h>
#include <hip/hip_bf16.h>

#define BATCH   2048
#define NFIELDS 32
#define EMBED   64
#define NPAIRS  496
#define BT      256   // batches per block (4 waves x 4 iters x 16)

typedef __attribute__((ext_vector_type(8))) short bf16x8;
typedef __attribute__((ext_vector_type(4))) float f32x4;

__device__ __forceinline__ unsigned short f2bf(float x) {
    unsigned int u = __float_as_uint(x);
    unsigned int r = 0x7fffu + ((u >> 16) & 1u);
    return (unsigned short)((u + r) >> 16);
}
__device__ __forceinline__ bf16x8 cvt8(const float* p) {
    float4 v0 = *(const float4*)p;
    float4 v1 = *(const float4*)(p + 4);
    bf16x8 o;
    o[0]=(short)f2bf(v0.x); o[1]=(short)f2bf(v0.y); o[2]=(short)f2bf(v0.z); o[3]=(short)f2bf(v0.w);
    o[4]=(short)f2bf(v1.x); o[5]=(short)f2bf(v1.y); o[6]=(short)f2bf(v1.z); o[7]=(short)f2bf(v1.w);
    return o;
}

// Prepass: emb fp32 -> bf16 (same layout); kernel fp32 [i][p][j] -> bf16 [p][i][j]
__global__ __launch_bounds__(256) void convert_prepass(
    const float* __restrict__ emb, const float* __restrict__ kern,
    unsigned short* __restrict__ embB, unsigned short* __restrict__ kernB)
{
    const int EMB4 = BATCH * NFIELDS * EMBED / 4;   // 1048576
    const int KER4 = EMBED * NPAIRS * EMBED / 4;    // 507904
    int t = blockIdx.x * blockDim.x + threadIdx.x;
    if (t < EMB4) {
        float4 v = ((const float4*)emb)[t];
        ushort4 o;
        o.x = f2bf(v.x); o.y = f2bf(v.y); o.z = f2bf(v.z); o.w = f2bf(v.w);
        *(ushort4*)(embB + (size_t)t * 4) = o;
    } else if (t < EMB4 + KER4) {
        int u = t - EMB4;
        int j4   = u & 15;
        int rest = u >> 4;
        int p = rest % NPAIRS;
        int i = rest / NPAIRS;
        float4 v = *(const float4*)(kern + (size_t)i * (NPAIRS*EMBED) + (size_t)p * EMBED + j4*4);
        ushort4 o;
        o.x = f2bf(v.x); o.y = f2bf(v.y); o.z = f2bf(v.z); o.w = f2bf(v.w);
        *(ushort4*)(kernB + (size_t)p * 4096 + i * 64 + j4 * 4) = o;
    }
}

// Main: block = (pair, 256-batch tile). 4 waves, each wave: 4 iters of 16 batches.
// kpT = K_p * P^T via MFMA (A = K_p from LDS-preloaded regs, B = P^T direct from
// global). D layout: i = 16*mt + quad*4 + rr, b = col. Then out[b] = sum_i q[b,i]*kpT[i,b]
// with q read directly from global as 8B chunks; reduce across quads (2 shuffles).
template<bool PRE>
__global__ __launch_bounds__(256) void opn_main(
    const void* __restrict__ embP, const void* __restrict__ kernP,
    float* __restrict__ out)
{
    const int pair = blockIdx.x;
    const int bt   = blockIdx.y;

    // decode pair -> (r, c) triu k=1, row-major
    int r = 0, s0 = 0;
    while (pair >= s0 + (NFIELDS - 1 - r)) { s0 += NFIELDS - 1 - r; ++r; }
    const int c = r + 1 + (pair - s0);

    __shared__ __align__(16) unsigned short Klds[64][72];   // +8 pad

    const int tid = threadIdx.x;

    // ---- stage K_pair (64x64 bf16) into LDS (once per block) ----
    if (PRE) {
        const unsigned short* kb = (const unsigned short*)kernP + (size_t)pair * 4096;
        #pragma unroll
        for (int itk = 0; itk < 2; ++itk) {
            int idx = (itk * 256 + tid) * 8;
            *(bf16x8*)&Klds[idx >> 6][idx & 63] = *(const bf16x8*)(kb + idx);
        }
    } else {
        const float* kf = (const float*)kernP;
        #pragma unroll
        for (int itk = 0; itk < 2; ++itk) {
            int idx = (itk * 256 + tid) * 8;
            int i = idx >> 6, j = idx & 63;
            *(bf16x8*)&Klds[i][j] = cvt8(kf + (size_t)i * (NPAIRS*EMBED) + (size_t)pair * EMBED + j);
        }
    }
    __syncthreads();

    const int wave = tid >> 6, lane = tid & 63;
    const int col = lane & 15, quad = lane >> 4;

    // Preload K as A-fragments: kfr[mt][ks] = A[m = 16mt+col][k = 32ks + quad*8 + t]
    bf16x8 kfr[4][2];
    #pragma unroll
    for (int mt = 0; mt < 4; ++mt)
        #pragma unroll
        for (int ks = 0; ks < 2; ++ks)
            kfr[mt][ks] = *(const bf16x8*)&Klds[mt*16 + col][ks*32 + quad*8];

    const unsigned short* eb = (const unsigned short*)embP;
    const float* ef = (const float*)embP;

    #pragma unroll
    for (int it = 0; it < 4; ++it) {
        const int b = bt * BT + wave * 64 + it * 16 + col;
        const size_t rowbase = (size_t)b * (NFIELDS * EMBED);

        // B = P^T fragments, direct from global: B[k=32s+quad*8+t][n=col] = p[b][32s+quad*8+t]
        bf16x8 pfr[2];
        if (PRE) {
            pfr[0] = *(const bf16x8*)(eb + rowbase + (size_t)r * EMBED + quad*8);
            pfr[1] = *(const bf16x8*)(eb + rowbase + (size_t)r * EMBED + 32 + quad*8);
        } else {
            pfr[0] = cvt8(ef + rowbase + (size_t)r * EMBED + quad*8);
            pfr[1] = cvt8(ef + rowbase + (size_t)r * EMBED + 32 + quad*8);
        }

        f32x4 acc[4];
        #pragma unroll
        for (int mt = 0; mt < 4; ++mt) {
            acc[mt] = (f32x4){0.f, 0.f, 0.f, 0.f};
            acc[mt] = __builtin_amdgcn_mfma_f32_16x16x32_bf16(kfr[mt][0], pfr[0], acc[mt], 0, 0, 0);
            acc[mt] = __builtin_amdgcn_mfma_f32_16x16x32_bf16(kfr[mt][1], pfr[1], acc[mt], 0, 0, 0);
        }

        // epilogue: out[b] = sum_i q[b,i] * kpT[i,b]; lane holds i = 16mt+quad*4+rr at b=col
        float partial = 0.f;
        #pragma unroll
        for (int mt = 0; mt < 4; ++mt) {
            float qv0, qv1, qv2, qv3;
            if (PRE) {
                uint2 qd = *(const uint2*)(eb + rowbase + (size_t)c * EMBED + mt*16 + quad*4);
                qv0 = __uint_as_float(qd.x << 16);
                qv1 = __uint_as_float(qd.x & 0xffff0000u);
                qv2 = __uint_as_float(qd.y << 16);
                qv3 = __uint_as_float(qd.y & 0xffff0000u);
            } else {
                float4 qf = *(const float4*)(ef + rowbase + (size_t)c * EMBED + mt*16 + quad*4);
                qv0 = qf.x; qv1 = qf.y; qv2 = qf.z; qv3 = qf.w;
            }
            partial += acc[mt][0] * qv0;
            partial += acc[mt][1] * qv1;
            partial += acc[mt][2] * qv2;
            partial += acc[mt][3] * qv3;
        }
        partial += __shfl_xor(partial, 16, 64);
        partial += __shfl_xor(partial, 32, 64);

        if (quad == 0)
            out[(size_t)b * NPAIRS + pair] = partial;
    }
}

extern "C" void kernel_launch(void* const* d_in, const int* in_sizes, int n_in,
                              void* d_out, int out_size, void* d_ws, size_t ws_size,
                              hipStream_t stream) {
    const float* emb  = (const float*)d_in[0];   // (2048, 32, 64) fp32
    const float* kern = (const float*)d_in[1];   // (64, 496, 64) fp32
    float* out = (float*)d_out;                  // (2048, 1, 496) fp32

    const size_t embElems  = (size_t)BATCH * NFIELDS * EMBED;   // 4194304
    const size_t kernElems = (size_t)EMBED * NPAIRS * EMBED;    // 2031616
    const size_t need = (embElems + kernElems) * sizeof(unsigned short);

    dim3 grid(NPAIRS, BATCH / BT);
    if (ws_size >= need) {
        unsigned short* embB  = (unsigned short*)d_ws;
        unsigned short* kernB = embB + embElems;
        int total4 = (int)((embElems + kernElems) / 4);
        convert_prepass<<<(total4 + 255) / 256, 256, 0, stream>>>(emb, kern, embB, kernB);
        opn_main<true><<<grid, 256, 0, stream>>>((const void*)embB, (const void*)kernB, out);
    } else {
        opn_main<false><<<grid, 256, 0, stream>>>((const void*)emb, (const void*)kern, out);
    }
}

// Round 3
// 119.194 us; speedup vs baseline: 1.0010x; 1.0010x over previous
//
#include <hip/hip_runtime.h>
#include <hip/hip_bf16.h>

#define BATCH   2048
#define NFIELDS 32
#define EMBED   64
#define NPAIRS  496
#define BT      512            // batches per block
#define NIT     (BT / 64)      // 16-batch tiles per wave = 8

typedef __attribute__((ext_vector_type(8))) short bf16x8;
typedef __attribute__((ext_vector_type(4))) float f32x4;

__device__ __forceinline__ unsigned short f2bf(float x) {
    unsigned int u = __float_as_uint(x);
    unsigned int r = 0x7fffu + ((u >> 16) & 1u);
    return (unsigned short)((u + r) >> 16);
}
__device__ __forceinline__ bf16x8 cvt8(const float* p) {
    float4 v0 = *(const float4*)p;
    float4 v1 = *(const float4*)(p + 4);
    bf16x8 o;
    o[0]=(short)f2bf(v0.x); o[1]=(short)f2bf(v0.y); o[2]=(short)f2bf(v0.z); o[3]=(short)f2bf(v0.w);
    o[4]=(short)f2bf(v1.x); o[5]=(short)f2bf(v1.y); o[6]=(short)f2bf(v1.z); o[7]=(short)f2bf(v1.w);
    return o;
}

// Prepass:
//   emb fp32 [b][f][e]  -> bf16 embT [f][b][e]   (batch-contiguous per field)
//   kern fp32 [i][p][j] -> bf16 kernB [p][i][j]  (per-pair contiguous)
__global__ __launch_bounds__(256) void convert_prepass(
    const float* __restrict__ emb, const float* __restrict__ kern,
    unsigned short* __restrict__ embT, unsigned short* __restrict__ kernB)
{
    const int EMB4 = BATCH * NFIELDS * EMBED / 4;   // 1048576
    const int KER4 = EMBED * NPAIRS * EMBED / 4;    // 507904
    int t = blockIdx.x * blockDim.x + threadIdx.x;
    if (t < EMB4) {
        int e4 = t & 15;                 // embed quarter (4 floats)
        int b  = (t >> 4) & (BATCH - 1);
        int f  = t >> 15;                // 0..31
        float4 v = *(const float4*)(emb + ((size_t)b * NFIELDS + f) * EMBED + e4 * 4);
        ushort4 o;
        o.x = f2bf(v.x); o.y = f2bf(v.y); o.z = f2bf(v.z); o.w = f2bf(v.w);
        *(ushort4*)(embT + ((size_t)f * BATCH + b) * EMBED + e4 * 4) = o;
    } else if (t < EMB4 + KER4) {
        int u = t - EMB4;
        int j4   = u & 15;
        int rest = u >> 4;
        int p = rest % NPAIRS;
        int i = rest / NPAIRS;
        float4 v = *(const float4*)(kern + (size_t)i * (NPAIRS*EMBED) + (size_t)p * EMBED + j4*4);
        ushort4 o;
        o.x = f2bf(v.x); o.y = f2bf(v.y); o.z = f2bf(v.z); o.w = f2bf(v.w);
        *(ushort4*)(kernB + (size_t)p * 4096 + i * 64 + j4 * 4) = o;
    }
}

// Main: block = (pair, 512-batch tile). kpT = K_p * P^T via MFMA; A = K_p (LDS-preloaded
// regs), B = P^T streamed coalesced from embT. Depth-2 register pipeline on p/q loads.
template<bool PRE>
__global__ __launch_bounds__(256) void opn_main(
    const void* __restrict__ embP, const void* __restrict__ kernP,
    float* __restrict__ out)
{
    const int pair = blockIdx.x;
    const int bt   = blockIdx.y;

    int r = 0, s0 = 0;
    while (pair >= s0 + (NFIELDS - 1 - r)) { s0 += NFIELDS - 1 - r; ++r; }
    const int c = r + 1 + (pair - s0);

    __shared__ __align__(16) unsigned short Klds[64][72];
    const int tid = threadIdx.x;

    if (PRE) {
        const unsigned short* kb = (const unsigned short*)kernP + (size_t)pair * 4096;
        #pragma unroll
        for (int itk = 0; itk < 2; ++itk) {
            int idx = (itk * 256 + tid) * 8;
            *(bf16x8*)&Klds[idx >> 6][idx & 63] = *(const bf16x8*)(kb + idx);
        }
    } else {
        const float* kf = (const float*)kernP;
        #pragma unroll
        for (int itk = 0; itk < 2; ++itk) {
            int idx = (itk * 256 + tid) * 8;
            int i = idx >> 6, j = idx & 63;
            *(bf16x8*)&Klds[i][j] = cvt8(kf + (size_t)i * (NPAIRS*EMBED) + (size_t)pair * EMBED + j);
        }
    }
    __syncthreads();

    const int wave = tid >> 6, lane = tid & 63;
    const int col = lane & 15, quad = lane >> 4;

    // K as A-fragments: kfr[mt][ks] = A[m=16mt+col][k=32ks+quad*8+t]
    bf16x8 kfr[4][2];
    #pragma unroll
    for (int mt = 0; mt < 4; ++mt)
        #pragma unroll
        for (int ks = 0; ks < 2; ++ks)
            kfr[mt][ks] = *(const bf16x8*)&Klds[mt*16 + col][ks*32 + quad*8];

    const unsigned short* prow = (const unsigned short*)embP + ((size_t)r * BATCH) * EMBED;
    const unsigned short* qrow = (const unsigned short*)embP + ((size_t)c * BATCH) * EMBED;
    const float* ef = (const float*)embP;

    const int b0base = bt * BT + wave * (BT / 4);

    bf16x8 pfA[2], pfB[2];
    uint2  qv[2][4];
    float4 qf[2][4];   // PRE=false path

    // prefetch tile 0
    {
        const size_t eo = (size_t)(b0base + col) * EMBED;
        if (PRE) {
            pfA[0] = *(const bf16x8*)(prow + eo + quad*8);
            pfB[0] = *(const bf16x8*)(prow + eo + 32 + quad*8);
            #pragma unroll
            for (int mt = 0; mt < 4; ++mt)
                qv[0][mt] = *(const uint2*)(qrow + eo + mt*16 + quad*4);
        } else {
            const size_t rb = (size_t)(b0base + col) * (NFIELDS * EMBED);
            pfA[0] = cvt8(ef + rb + (size_t)r * EMBED + quad*8);
            pfB[0] = cvt8(ef + rb + (size_t)r * EMBED + 32 + quad*8);
            #pragma unroll
            for (int mt = 0; mt < 4; ++mt)
                qf[0][mt] = *(const float4*)(ef + rb + (size_t)c * EMBED + mt*16 + quad*4);
        }
    }

    #pragma unroll
    for (int it = 0; it < NIT; ++it) {
        const int cur = it & 1, nxt = cur ^ 1;
        if (it + 1 < NIT) {
            const size_t eo = (size_t)(b0base + (it+1)*16 + col) * EMBED;
            if (PRE) {
                pfA[nxt] = *(const bf16x8*)(prow + eo + quad*8);
                pfB[nxt] = *(const bf16x8*)(prow + eo + 32 + quad*8);
                #pragma unroll
                for (int mt = 0; mt < 4; ++mt)
                    qv[nxt][mt] = *(const uint2*)(qrow + eo + mt*16 + quad*4);
            } else {
                const size_t rb = (size_t)(b0base + (it+1)*16 + col) * (NFIELDS * EMBED);
                pfA[nxt] = cvt8(ef + rb + (size_t)r * EMBED + quad*8);
                pfB[nxt] = cvt8(ef + rb + (size_t)r * EMBED + 32 + quad*8);
                #pragma unroll
                for (int mt = 0; mt < 4; ++mt)
                    qf[nxt][mt] = *(const float4*)(ef + rb + (size_t)c * EMBED + mt*16 + quad*4);
            }
        }

        f32x4 acc[4];
        #pragma unroll
        for (int mt = 0; mt < 4; ++mt) {
            acc[mt] = (f32x4){0.f, 0.f, 0.f, 0.f};
            acc[mt] = __builtin_amdgcn_mfma_f32_16x16x32_bf16(kfr[mt][0], pfA[cur], acc[mt], 0, 0, 0);
            acc[mt] = __builtin_amdgcn_mfma_f32_16x16x32_bf16(kfr[mt][1], pfB[cur], acc[mt], 0, 0, 0);
        }

        float partial = 0.f;
        #pragma unroll
        for (int mt = 0; mt < 4; ++mt) {
            float qv0, qv1, qv2, qv3;
            if (PRE) {
                uint2 qd = qv[cur][mt];
                qv0 = __uint_as_float(qd.x << 16);
                qv1 = __uint_as_float(qd.x & 0xffff0000u);
                qv2 = __uint_as_float(qd.y << 16);
                qv3 = __uint_as_float(qd.y & 0xffff0000u);
            } else {
                float4 q4 = qf[cur][mt];
                qv0 = q4.x; qv1 = q4.y; qv2 = q4.z; qv3 = q4.w;
            }
            partial += acc[mt][0] * qv0;
            partial += acc[mt][1] * qv1;
            partial += acc[mt][2] * qv2;
            partial += acc[mt][3] * qv3;
        }
        partial += __shfl_xor(partial, 16, 64);
        partial += __shfl_xor(partial, 32, 64);

        if (quad == 0) {
            const int b = b0base + it*16 + col;
            out[(size_t)b * NPAIRS + pair] = partial;
        }
    }
}

extern "C" void kernel_launch(void* const* d_in, const int* in_sizes, int n_in,
                              void* d_out, int out_size, void* d_ws, size_t ws_size,
                              hipStream_t stream) {
    const float* emb  = (const float*)d_in[0];   // (2048, 32, 64) fp32
    const float* kern = (const float*)d_in[1];   // (64, 496, 64) fp32
    float* out = (float*)d_out;                  // (2048, 1, 496) fp32

    const size_t embElems  = (size_t)BATCH * NFIELDS * EMBED;   // 4194304
    const size_t kernElems = (size_t)EMBED * NPAIRS * EMBED;    // 2031616
    const size_t need = (embElems + kernElems) * sizeof(unsigned short);

    dim3 grid(NPAIRS, BATCH / BT);
    if (ws_size >= need) {
        unsigned short* embT  = (unsigned short*)d_ws;
        unsigned short* kernB = embT + embElems;
        int total4 = (int)((embElems + kernElems) / 4);
        convert_prepass<<<(total4 + 255) / 256, 256, 0, stream>>>(emb, kern, embT, kernB);
        opn_main<true><<<grid, 256, 0, stream>>>((const void*)embT, (const void*)kernB, out);
    } else {
        opn_main<false><<<grid, 256, 0, stream>>>((const void*)emb, (const void*)kern, out);
    }
}

// Round 4
// 111.719 us; speedup vs baseline: 1.0680x; 1.0669x over previous
//
#include <hip/hip_runtime.h>
#include <hip/hip_bf16.h>

#define BATCH   2048
#define NFIELDS 32
#define EMBED   64
#define NPAIRS  496
#define BT      512            // batches per block
#define NIT     8              // 16-batch tiles per wave  (BT/64)
#define TPB     32             // 16-batch tiles per block (BT/16)

typedef __attribute__((ext_vector_type(8))) short bf16x8;
typedef __attribute__((ext_vector_type(4))) float f32x4;

__device__ __forceinline__ unsigned short f2bf(float x) {
    unsigned int u = __float_as_uint(x);
    unsigned int r = 0x7fffu + ((u >> 16) & 1u);
    return (unsigned short)((u + r) >> 16);
}

// ws layout (ushort elems):
//   embPp [f][t][ks][quad][col][8]   f<32,t<128,ks<2,quad<4,col<16 : 4194304 elems
//   embPq [f][t][mt2][quad][col][8]  entry = {q[mt2*32+quad*4+0..3], q[mt2*32+16+quad*4+0..3]}
//                                    : 4194304 elems
//   kernB [p][i][j]                  : 2031616 elems
#define PP_OFF 0
#define PQ_OFF 4194304
#define KB_OFF 8388608
#define WS_ELEMS 10420224

__global__ __launch_bounds__(256) void prepass(
    const float* __restrict__ emb, const float* __restrict__ kern,
    unsigned short* __restrict__ ws)
{
    unsigned short* pp = ws + PP_OFF;
    unsigned short* pq = ws + PQ_OFF;
    unsigned short* kb = ws + KB_OFF;
    const int NEMB8 = BATCH * NFIELDS * EMBED / 8;   // 524288
    const int NKER8 = EMBED * NPAIRS * EMBED / 8;    // 253952
    int v = blockIdx.x * blockDim.x + threadIdx.x;
    if (v < NEMB8) {
        int base = v * 8;
        int e0 = base & 63;              // multiple of 8
        int f  = (base >> 6) & 31;
        int b  = base >> 11;
        float4 v0 = *(const float4*)(emb + base);
        float4 v1 = *(const float4*)(emb + base + 4);
        ushort4 lo, hi;
        lo.x = f2bf(v0.x); lo.y = f2bf(v0.y); lo.z = f2bf(v0.z); lo.w = f2bf(v0.w);
        hi.x = f2bf(v1.x); hi.y = f2bf(v1.y); hi.z = f2bf(v1.z); hi.w = f2bf(v1.w);
        int t = b >> 4, col = b & 15;
        int ks = e0 >> 5, quad = (e0 & 31) >> 3;
        size_t dp = (size_t)f * 131072 + t * 1024 + ks * 512 + quad * 128 + col * 8;
        *(ushort4*)(pp + dp)     = lo;
        *(ushort4*)(pp + dp + 4) = hi;
        // q fragment-order: mt2 = e0/32; pos = e0%32 in {0,8,16,24}
        int pos  = e0 & 31;
        int half = pos >> 4;                 // 0,1
        int qq   = (pos & 15) >> 2;          // 0 or 2; second 4-group -> qq+1
        size_t dq = (size_t)f * 131072 + t * 1024 + ks * 512 + qq * 128 + col * 8 + half * 4;
        *(ushort4*)(pq + dq)       = lo;
        *(ushort4*)(pq + dq + 128) = hi;     // quad+1 entry, same half
    } else if (v < NEMB8 + NKER8) {
        int base = (v - NEMB8) * 8;
        int j0 = base & 63;
        int pr = (base >> 6) % NPAIRS;
        int i  = (base >> 6) / NPAIRS;
        float4 v0 = *(const float4*)(kern + base);
        float4 v1 = *(const float4*)(kern + base + 4);
        ushort4 lo, hi;
        lo.x = f2bf(v0.x); lo.y = f2bf(v0.y); lo.z = f2bf(v0.z); lo.w = f2bf(v0.w);
        hi.x = f2bf(v1.x); hi.y = f2bf(v1.y); hi.z = f2bf(v1.z); hi.w = f2bf(v1.w);
        size_t dk = (size_t)pr * 4096 + i * 64 + j0;
        *(ushort4*)(kb + dk)     = lo;
        *(ushort4*)(kb + dk + 4) = hi;
    }
}

// Main: no LDS, no barriers. K-fragments gathered once per block; p/q fragment
// streams are lane-linear 1KB bursts. Depth-2 register pipeline.
__global__ __launch_bounds__(256) void opn_main(
    const unsigned short* __restrict__ ws, float* __restrict__ out)
{
    const unsigned short* pp = ws + PP_OFF;
    const unsigned short* pq = ws + PQ_OFF;
    const unsigned short* kb = ws + KB_OFF;

    const int pair = blockIdx.x;
    const int bt   = blockIdx.y;
    int r = 0, s0 = 0;
    while (pair >= s0 + (NFIELDS - 1 - r)) { s0 += NFIELDS - 1 - r; ++r; }
    const int c = r + 1 + (pair - s0);

    const int tid = threadIdx.x;
    const int wave = tid >> 6, lane = tid & 63;
    const int col = lane & 15, quad = lane >> 4;

    // A = K_p fragments: kfr[mt][ks] = K[m=mt*16+col][k=ks*32+quad*8+..]
    bf16x8 kfr[4][2];
    const unsigned short* kp = kb + (size_t)pair * 4096;
    #pragma unroll
    for (int mt = 0; mt < 4; ++mt)
        #pragma unroll
        for (int ks = 0; ks < 2; ++ks)
            kfr[mt][ks] = *(const bf16x8*)(kp + (mt*16 + col)*64 + ks*32 + quad*8);

    const int T0 = bt * TPB + wave * NIT;
    const unsigned short* pbase = pp + (size_t)r * 131072 + (size_t)T0 * 1024 + lane * 8;
    const unsigned short* qbase = pq + (size_t)c * 131072 + (size_t)T0 * 1024 + lane * 8;

    bf16x8 pA[2], pB[2];
    uint4  qA[2], qB[2];
    pA[0] = *(const bf16x8*)(pbase);
    pB[0] = *(const bf16x8*)(pbase + 512);
    qA[0] = *(const uint4*)(qbase);
    qB[0] = *(const uint4*)(qbase + 512);

    #pragma unroll
    for (int it = 0; it < NIT; ++it) {
        const int cur = it & 1, nxt = cur ^ 1;
        if (it + 1 < NIT) {
            pA[nxt] = *(const bf16x8*)(pbase + (it+1)*1024);
            pB[nxt] = *(const bf16x8*)(pbase + (it+1)*1024 + 512);
            qA[nxt] = *(const uint4*)(qbase + (it+1)*1024);
            qB[nxt] = *(const uint4*)(qbase + (it+1)*1024 + 512);
        }

        f32x4 acc[4];
        #pragma unroll
        for (int mt = 0; mt < 4; ++mt) {
            acc[mt] = (f32x4){0.f, 0.f, 0.f, 0.f};
            acc[mt] = __builtin_amdgcn_mfma_f32_16x16x32_bf16(kfr[mt][0], pA[cur], acc[mt], 0, 0, 0);
            acc[mt] = __builtin_amdgcn_mfma_f32_16x16x32_bf16(kfr[mt][1], pB[cur], acc[mt], 0, 0, 0);
        }

        // epilogue: i = mt*16 + quad*4 + rr at batch col; q pre-shuffled to match
        float partial = 0.f;
        {
            uint4 qa = qA[cur], qb = qB[cur];
            partial += acc[0][0] * __uint_as_float(qa.x << 16);
            partial += acc[0][1] * __uint_as_float(qa.x & 0xffff0000u);
            partial += acc[0][2] * __uint_as_float(qa.y << 16);
            partial += acc[0][3] * __uint_as_float(qa.y & 0xffff0000u);
            partial += acc[1][0] * __uint_as_float(qa.z << 16);
            partial += acc[1][1] * __uint_as_float(qa.z & 0xffff0000u);
            partial += acc[1][2] * __uint_as_float(qa.w << 16);
            partial += acc[1][3] * __uint_as_float(qa.w & 0xffff0000u);
            partial += acc[2][0] * __uint_as_float(qb.x << 16);
            partial += acc[2][1] * __uint_as_float(qb.x & 0xffff0000u);
            partial += acc[2][2] * __uint_as_float(qb.y << 16);
            partial += acc[2][3] * __uint_as_float(qb.y & 0xffff0000u);
            partial += acc[3][0] * __uint_as_float(qb.z << 16);
            partial += acc[3][1] * __uint_as_float(qb.z & 0xffff0000u);
            partial += acc[3][2] * __uint_as_float(qb.w << 16);
            partial += acc[3][3] * __uint_as_float(qb.w & 0xffff0000u);
        }
        partial += __shfl_xor(partial, 16, 64);
        partial += __shfl_xor(partial, 32, 64);

        if (quad == 0)
            out[(size_t)((T0 + it) * 16 + col) * NPAIRS + pair] = partial;
    }
}

// Fallback (ws too small — not expected to run): plain fp32 per-(b,p) dot.
__global__ __launch_bounds__(256) void opn_naive(
    const float* __restrict__ emb, const float* __restrict__ kern,
    float* __restrict__ out)
{
    int idx = blockIdx.x * blockDim.x + threadIdx.x;
    if (idx >= BATCH * NPAIRS) return;
    int b = idx / NPAIRS, p = idx % NPAIRS;
    int r = 0, s0 = 0;
    while (p >= s0 + (NFIELDS - 1 - r)) { s0 += NFIELDS - 1 - r; ++r; }
    int c = r + 1 + (p - s0);
    const float* pv = emb + ((size_t)b * NFIELDS + r) * EMBED;
    const float* qv = emb + ((size_t)b * NFIELDS + c) * EMBED;
    float acc = 0.f;
    for (int i = 0; i < EMBED; ++i) {
        const float* kr = kern + ((size_t)i * NPAIRS + p) * EMBED;
        float kpv = 0.f;
        for (int j = 0; j < EMBED; ++j) kpv += kr[j] * pv[j];
        acc += kpv * qv[i];
    }
    out[(size_t)b * NPAIRS + p] = acc;
}

extern "C" void kernel_launch(void* const* d_in, const int* in_sizes, int n_in,
                              void* d_out, int out_size, void* d_ws, size_t ws_size,
                              hipStream_t stream) {
    const float* emb  = (const float*)d_in[0];   // (2048, 32, 64) fp32
    const float* kern = (const float*)d_in[1];   // (64, 496, 64) fp32
    float* out = (float*)d_out;                  // (2048, 1, 496) fp32

    if (ws_size >= (size_t)WS_ELEMS * sizeof(unsigned short)) {
        unsigned short* ws = (unsigned short*)d_ws;
        const int NEMB8 = BATCH * NFIELDS * EMBED / 8;
        const int NKER8 = EMBED * NPAIRS * EMBED / 8;
        int total = NEMB8 + NKER8;
        prepass<<<(total + 255) / 256, 256, 0, stream>>>(emb, kern, ws);
        dim3 grid(NPAIRS, BATCH / BT);
        opn_main<<<grid, 256, 0, stream>>>(ws, out);
    } else {
        int total = BATCH * NPAIRS;
        opn_naive<<<(total + 255) / 256, 256, 0, stream>>>(emb, kern, out);
    }
}

// Round 5
// 109.855 us; speedup vs baseline: 1.0861x; 1.0170x over previous
//
#include <hip/hip_runtime.h>
#include <hip/hip_bf16.h>

#define BATCH   2048
#define NFIELDS 32
#define EMBED   64
#define NPAIRS  496
#define BT      256            // batches per block
#define NIT     4              // 16-batch tiles per wave  (BT/64)
#define TPB     16             // 16-batch tiles per block (BT/16)
#define NBT     (BATCH / BT)   // 8 batch-tiles
#define PPX     62             // pairs per XCD slice (496/8)

typedef __attribute__((ext_vector_type(8))) short bf16x8;
typedef __attribute__((ext_vector_type(4))) float f32x4;

__device__ __forceinline__ unsigned short f2bf(float x) {
    unsigned int u = __float_as_uint(x);
    unsigned int r = 0x7fffu + ((u >> 16) & 1u);
    return (unsigned short)((u + r) >> 16);
}

// ws layout (ushort elems):
//   embPp [f][t][ks][quad][col][8]   f<32,t<128,ks<2,quad<4,col<16 : 4194304 elems
//   embPq [f][t][mt2][quad][col][8]  (q pre-shuffled into C/D-layout order) : 4194304
//   kernB [p][i][j]                  : 2031616 elems
#define PP_OFF 0
#define PQ_OFF 4194304
#define KB_OFF 8388608
#define WS_ELEMS 10420224

__global__ __launch_bounds__(256) void prepass(
    const float* __restrict__ emb, const float* __restrict__ kern,
    unsigned short* __restrict__ ws)
{
    unsigned short* pp = ws + PP_OFF;
    unsigned short* pq = ws + PQ_OFF;
    unsigned short* kb = ws + KB_OFF;
    const int NEMB8 = BATCH * NFIELDS * EMBED / 8;   // 524288
    const int NKER8 = EMBED * NPAIRS * EMBED / 8;    // 253952
    int v = blockIdx.x * blockDim.x + threadIdx.x;
    if (v < NEMB8) {
        int base = v * 8;
        int e0 = base & 63;              // multiple of 8
        int f  = (base >> 6) & 31;
        int b  = base >> 11;
        float4 v0 = *(const float4*)(emb + base);
        float4 v1 = *(const float4*)(emb + base + 4);
        ushort4 lo, hi;
        lo.x = f2bf(v0.x); lo.y = f2bf(v0.y); lo.z = f2bf(v0.z); lo.w = f2bf(v0.w);
        hi.x = f2bf(v1.x); hi.y = f2bf(v1.y); hi.z = f2bf(v1.z); hi.w = f2bf(v1.w);
        int t = b >> 4, col = b & 15;
        int ks = e0 >> 5, quad = (e0 & 31) >> 3;
        size_t dp = (size_t)f * 131072 + t * 1024 + ks * 512 + quad * 128 + col * 8;
        *(ushort4*)(pp + dp)     = lo;
        *(ushort4*)(pp + dp + 4) = hi;
        // q fragment-order
        int pos  = e0 & 31;
        int half = pos >> 4;                 // 0,1
        int qq   = (pos & 15) >> 2;          // 0 or 2
        size_t dq = (size_t)f * 131072 + t * 1024 + ks * 512 + qq * 128 + col * 8 + half * 4;
        *(ushort4*)(pq + dq)       = lo;
        *(ushort4*)(pq + dq + 128) = hi;
    } else if (v < NEMB8 + NKER8) {
        int base = (v - NEMB8) * 8;
        int j0 = base & 63;
        int pr = (base >> 6) % NPAIRS;
        int i  = (base >> 6) / NPAIRS;
        float4 v0 = *(const float4*)(kern + base);
        float4 v1 = *(const float4*)(kern + base + 4);
        ushort4 lo, hi;
        lo.x = f2bf(v0.x); lo.y = f2bf(v0.y); lo.z = f2bf(v0.z); lo.w = f2bf(v0.w);
        hi.x = f2bf(v1.x); hi.y = f2bf(v1.y); hi.z = f2bf(v1.z); hi.w = f2bf(v1.w);
        size_t dk = (size_t)pr * 4096 + i * 64 + j0;
        *(ushort4*)(kb + dk)     = lo;
        *(ushort4*)(kb + dk + 4) = hi;
    }
}

// Main: no LDS, no barriers. Per wave: preload K-fragments, then issue ALL 16
// stream loads for its 4 batch-tiles up front (16 outstanding VMEM), then compute.
// Block swizzle: xcd = bx&7 owns a contiguous 62-pair slice (L2 affinity for
// shared p-streams and K slice).
__global__ __launch_bounds__(256) void opn_main(
    const unsigned short* __restrict__ ws, float* __restrict__ out)
{
    const unsigned short* pp = ws + PP_OFF;
    const unsigned short* pq = ws + PQ_OFF;
    const unsigned short* kb = ws + KB_OFF;

    const int bx   = blockIdx.x;            // 0..3967
    const int slot = bx >> 3;               // 0..495
    const int pair = (bx & 7) * PPX + slot % PPX;
    const int bt   = slot / PPX;            // 0..7

    int r = 0, s0 = 0;
    while (pair >= s0 + (NFIELDS - 1 - r)) { s0 += NFIELDS - 1 - r; ++r; }
    const int c = r + 1 + (pair - s0);

    const int tid = threadIdx.x;
    const int wave = tid >> 6, lane = tid & 63;
    const int col = lane & 15, quad = lane >> 4;

    // A = K_p fragments: kfr[mt][ks] = K[m=mt*16+col][k=ks*32+quad*8+..]
    bf16x8 kfr[4][2];
    const unsigned short* kp = kb + (size_t)pair * 4096;
    #pragma unroll
    for (int mt = 0; mt < 4; ++mt)
        #pragma unroll
        for (int ks = 0; ks < 2; ++ks)
            kfr[mt][ks] = *(const bf16x8*)(kp + (mt*16 + col)*64 + ks*32 + quad*8);

    const int T0 = bt * TPB + wave * NIT;
    const unsigned short* pbase = pp + (size_t)r * 131072 + (size_t)T0 * 1024 + lane * 8;
    const unsigned short* qbase = pq + (size_t)c * 131072 + (size_t)T0 * 1024 + lane * 8;

    // issue all stream loads up front
    bf16x8 pA[NIT], pB[NIT];
    uint4  qA[NIT], qB[NIT];
    #pragma unroll
    for (int it = 0; it < NIT; ++it) {
        pA[it] = *(const bf16x8*)(pbase + it*1024);
        pB[it] = *(const bf16x8*)(pbase + it*1024 + 512);
        qA[it] = *(const uint4*)(qbase + it*1024);
        qB[it] = *(const uint4*)(qbase + it*1024 + 512);
    }

    #pragma unroll
    for (int it = 0; it < NIT; ++it) {
        f32x4 acc[4];
        #pragma unroll
        for (int mt = 0; mt < 4; ++mt) {
            acc[mt] = (f32x4){0.f, 0.f, 0.f, 0.f};
            acc[mt] = __builtin_amdgcn_mfma_f32_16x16x32_bf16(kfr[mt][0], pA[it], acc[mt], 0, 0, 0);
            acc[mt] = __builtin_amdgcn_mfma_f32_16x16x32_bf16(kfr[mt][1], pB[it], acc[mt], 0, 0, 0);
        }

        float partial = 0.f;
        {
            uint4 qa = qA[it], qb = qB[it];
            partial += acc[0][0] * __uint_as_float(qa.x << 16);
            partial += acc[0][1] * __uint_as_float(qa.x & 0xffff0000u);
            partial += acc[0][2] * __uint_as_float(qa.y << 16);
            partial += acc[0][3] * __uint_as_float(qa.y & 0xffff0000u);
            partial += acc[1][0] * __uint_as_float(qa.z << 16);
            partial += acc[1][1] * __uint_as_float(qa.z & 0xffff0000u);
            partial += acc[1][2] * __uint_as_float(qa.w << 16);
            partial += acc[1][3] * __uint_as_float(qa.w & 0xffff0000u);
            partial += acc[2][0] * __uint_as_float(qb.x << 16);
            partial += acc[2][1] * __uint_as_float(qb.x & 0xffff0000u);
            partial += acc[2][2] * __uint_as_float(qb.y << 16);
            partial += acc[2][3] * __uint_as_float(qb.y & 0xffff0000u);
            partial += acc[3][0] * __uint_as_float(qb.z << 16);
            partial += acc[3][1] * __uint_as_float(qb.z & 0xffff0000u);
            partial += acc[3][2] * __uint_as_float(qb.w << 16);
            partial += acc[3][3] * __uint_as_float(qb.w & 0xffff0000u);
        }
        partial += __shfl_xor(partial, 16, 64);
        partial += __shfl_xor(partial, 32, 64);

        if (quad == 0)
            out[(size_t)((T0 + it) * 16 + col) * NPAIRS + pair] = partial;
    }
}

// Fallback (ws too small): plain fp32 per-(b,p) dot.
__global__ __launch_bounds__(256) void opn_naive(
    const float* __restrict__ emb, const float* __restrict__ kern,
    float* __restrict__ out)
{
    int idx = blockIdx.x * blockDim.x + threadIdx.x;
    if (idx >= BATCH * NPAIRS) return;
    int b = idx / NPAIRS, p = idx % NPAIRS;
    int r = 0, s0 = 0;
    while (p >= s0 + (NFIELDS - 1 - r)) { s0 += NFIELDS - 1 - r; ++r; }
    int c = r + 1 + (p - s0);
    const float* pv = emb + ((size_t)b * NFIELDS + r) * EMBED;
    const float* qv = emb + ((size_t)b * NFIELDS + c) * EMBED;
    float acc = 0.f;
    for (int i = 0; i < EMBED; ++i) {
        const float* kr = kern + ((size_t)i * NPAIRS + p) * EMBED;
        float kpv = 0.f;
        for (int j = 0; j < EMBED; ++j) kpv += kr[j] * pv[j];
        acc += kpv * qv[i];
    }
    out[(size_t)b * NPAIRS + p] = acc;
}

extern "C" void kernel_launch(void* const* d_in, const int* in_sizes, int n_in,
                              void* d_out, int out_size, void* d_ws, size_t ws_size,
                              hipStream_t stream) {
    const float* emb  = (const float*)d_in[0];   // (2048, 32, 64) fp32
    const float* kern = (const float*)d_in[1];   // (64, 496, 64) fp32
    float* out = (float*)d_out;                  // (2048, 1, 496) fp32

    if (ws_size >= (size_t)WS_ELEMS * sizeof(unsigned short)) {
        unsigned short* ws = (unsigned short*)d_ws;
        const int NEMB8 = BATCH * NFIELDS * EMBED / 8;
        const int NKER8 = EMBED * NPAIRS * EMBED / 8;
        int total = NEMB8 + NKER8;
        prepass<<<(total + 255) / 256, 256, 0, stream>>>(emb, kern, ws);
        opn_main<<<dim3(NPAIRS * NBT), 256, 0, stream>>>(ws, out);
    } else {
        int total = BATCH * NPAIRS;
        opn_naive<<<(total + 255) / 256, 256, 0, stream>>>(emb, kern, out);
    }
}

// Round 6
// 107.432 us; speedup vs baseline: 1.1106x; 1.0226x over previous
//
#include <hip/hip_runtime.h>
#include <hip/hip_bf16.h>

#define BATCH   2048
#define NFIELDS 32
#define EMBED   64
#define NPAIRS  496
#define BT      128            // batches per block
#define NIT     4              // tiles per chunk
#define NCH     2              // chunks (BT/16/NIT)
#define NBT     (BATCH / BT)   // 16 batch-tiles
#define NPG     (NPAIRS / 4)   // 124 pair-groups

typedef __attribute__((ext_vector_type(8))) short bf16x8;
typedef __attribute__((ext_vector_type(4))) float f32x4;

__device__ __forceinline__ unsigned short f2bf(float x) {
    unsigned int u = __float_as_uint(x);
    unsigned int r = 0x7fffu + ((u >> 16) & 1u);
    return (unsigned short)((u + r) >> 16);
}

// ws layout:
//   PP  [f][t][ks][quad][col][8] bf16 : 4194304 ushorts (8 MB)
//   KB  [p][i][j]                bf16 : 2031616 ushorts (4 MB)
//   outT [p][b]                  fp32 : 1015808 floats  (4 MB)
#define PP_OFF 0
#define KB_OFF 4194304
#define OT_OFF_BYTES 12451840          // (4194304+2031616)*2
#define WS_BYTES (OT_OFF_BYTES + 2048*496*4)

__global__ __launch_bounds__(256) void prepass(
    const float* __restrict__ emb, const float* __restrict__ kern,
    unsigned short* __restrict__ ws)
{
    unsigned short* pp = ws + PP_OFF;
    unsigned short* kb = ws + KB_OFF;
    const int NEMB8 = BATCH * NFIELDS * EMBED / 8;   // 524288
    const int NKER8 = EMBED * NPAIRS * EMBED / 8;    // 253952
    int v = blockIdx.x * blockDim.x + threadIdx.x;
    if (v < NEMB8) {
        int base = v * 8;
        int e0 = base & 63;
        int f  = (base >> 6) & 31;
        int b  = base >> 11;
        float4 v0 = *(const float4*)(emb + base);
        float4 v1 = *(const float4*)(emb + base + 4);
        ushort4 lo, hi;
        lo.x = f2bf(v0.x); lo.y = f2bf(v0.y); lo.z = f2bf(v0.z); lo.w = f2bf(v0.w);
        hi.x = f2bf(v1.x); hi.y = f2bf(v1.y); hi.z = f2bf(v1.z); hi.w = f2bf(v1.w);
        int t = b >> 4, col = b & 15;
        int ks = e0 >> 5, quad = (e0 & 31) >> 3;
        size_t dp = (size_t)f * 131072 + t * 1024 + ks * 512 + quad * 128 + col * 8;
        *(ushort4*)(pp + dp)     = lo;
        *(ushort4*)(pp + dp + 4) = hi;
    } else if (v < NEMB8 + NKER8) {
        int base = (v - NEMB8) * 8;
        int j0 = base & 63;
        int pr = (base >> 6) % NPAIRS;
        int i  = (base >> 6) / NPAIRS;
        float4 v0 = *(const float4*)(kern + base);
        float4 v1 = *(const float4*)(kern + base + 4);
        ushort4 lo, hi;
        lo.x = f2bf(v0.x); lo.y = f2bf(v0.y); lo.z = f2bf(v0.z); lo.w = f2bf(v0.w);
        hi.x = f2bf(v1.x); hi.y = f2bf(v1.y); hi.z = f2bf(v1.z); hi.w = f2bf(v1.w);
        size_t dk = (size_t)pr * 4096 + i * 64 + j0;
        *(ushort4*)(kb + dk)     = lo;
        *(ushort4*)(kb + dk + 4) = hi;
    }
}

// Main: block = (4 consecutive pairs, 128-batch tile); wave w owns pair 4g+w.
// All waves sweep the SAME batch-tiles -> shared p-streams dedupe in L1/L2.
// xcd = bx&7 gets fixed batch-slice -> per-XCD read set ~5 MB (mostly L2-resident).
// Output written coalesced to outT[p][b]; separate transpose kernel emits out[b][p].
__global__ __launch_bounds__(256) void opn_main(
    const unsigned short* __restrict__ ws, float* __restrict__ outT)
{
    const unsigned short* pp = ws + PP_OFF;
    const unsigned short* kb = ws + KB_OFF;

    const int bx = blockIdx.x;              // 0..1983
    const int t  = bx & 15;                 // batch-tile (xcd = t&7)
    const int g  = bx >> 4;                 // pair-group 0..123

    const int tid = threadIdx.x;
    const int wave = tid >> 6, lane = tid & 63;
    const int col = lane & 15, quad = lane >> 4;

    const int pair = g * 4 + wave;
    int r = 0, s0 = 0;
    while (pair >= s0 + (NFIELDS - 1 - r)) { s0 += NFIELDS - 1 - r; ++r; }
    const int c = r + 1 + (pair - s0);

    // K_p fragments (A-operand): kfr[mt][ks] = K[m=mt*16+col][k=ks*32+quad*8+..]
    bf16x8 kfr[4][2];
    const unsigned short* kp = kb + (size_t)pair * 4096;
    #pragma unroll
    for (int mt = 0; mt < 4; ++mt)
        #pragma unroll
        for (int ks = 0; ks < 2; ++ks)
            kfr[mt][ks] = *(const bf16x8*)(kp + (mt*16 + col)*64 + ks*32 + quad*8);

    const unsigned short* pfield = pp + (size_t)r * 131072;
    const unsigned short* qfield = pp + (size_t)c * 131072;
    const int qlaneoff = (quad >> 1) * 128 + col * 8 + (quad & 1) * 4;

    float* otp = outT + (size_t)pair * BATCH;

    #pragma unroll
    for (int s = 0; s < NCH; ++s) {
        const int T0 = t * (BT/16) + s * NIT;   // first 16-batch tile of chunk

        // issue all stream loads for the chunk up front
        bf16x8 pA[NIT], pB[NIT];
        uint2  qv[NIT][4];
        #pragma unroll
        for (int it = 0; it < NIT; ++it) {
            const unsigned short* pt = pfield + (size_t)(T0 + it) * 1024;
            const unsigned short* qt = qfield + (size_t)(T0 + it) * 1024;
            pA[it] = *(const bf16x8*)(pt + lane * 8);
            pB[it] = *(const bf16x8*)(pt + 512 + lane * 8);
            #pragma unroll
            for (int mt = 0; mt < 4; ++mt)
                qv[it][mt] = *(const uint2*)(qt + (mt >> 1) * 512 + (mt & 1) * 256 + qlaneoff);
        }

        #pragma unroll
        for (int it = 0; it < NIT; ++it) {
            f32x4 acc[4];
            #pragma unroll
            for (int mt = 0; mt < 4; ++mt) {
                acc[mt] = (f32x4){0.f, 0.f, 0.f, 0.f};
                acc[mt] = __builtin_amdgcn_mfma_f32_16x16x32_bf16(kfr[mt][0], pA[it], acc[mt], 0, 0, 0);
                acc[mt] = __builtin_amdgcn_mfma_f32_16x16x32_bf16(kfr[mt][1], pB[it], acc[mt], 0, 0, 0);
            }

            float partial = 0.f;
            #pragma unroll
            for (int mt = 0; mt < 4; ++mt) {
                uint2 qd = qv[it][mt];
                partial += acc[mt][0] * __uint_as_float(qd.x << 16);
                partial += acc[mt][1] * __uint_as_float(qd.x & 0xffff0000u);
                partial += acc[mt][2] * __uint_as_float(qd.y << 16);
                partial += acc[mt][3] * __uint_as_float(qd.y & 0xffff0000u);
            }
            partial += __shfl_xor(partial, 16, 64);
            partial += __shfl_xor(partial, 32, 64);

            if (quad == 0)
                otp[(T0 + it) * 16 + col] = partial;   // 16 contiguous floats
        }
    }
}

// Transpose outT[p][b] -> out[b][p], 32x32 LDS tiles, both sides coalesced.
__global__ __launch_bounds__(256) void transpose_out(
    const float* __restrict__ outT, float* __restrict__ out)
{
    __shared__ float tile[32][33];
    const int p0 = blockIdx.x * 32;
    const int b0 = blockIdx.y * 32;
    const int tx = threadIdx.x & 31, ty = threadIdx.x >> 5;
    #pragma unroll
    for (int k = 0; k < 4; ++k) {
        int p = p0 + ty + k * 8;
        if (p < NPAIRS)
            tile[ty + k * 8][tx] = outT[(size_t)p * BATCH + b0 + tx];
    }
    __syncthreads();
    #pragma unroll
    for (int k = 0; k < 4; ++k) {
        int b = b0 + ty + k * 8;
        if (p0 + tx < NPAIRS)
            out[(size_t)b * NPAIRS + p0 + tx] = tile[tx][ty + k * 8];
    }
}

// Fallback (ws too small): plain fp32 per-(b,p) dot.
__global__ __launch_bounds__(256) void opn_naive(
    const float* __restrict__ emb, const float* __restrict__ kern,
    float* __restrict__ out)
{
    int idx = blockIdx.x * blockDim.x + threadIdx.x;
    if (idx >= BATCH * NPAIRS) return;
    int b = idx / NPAIRS, p = idx % NPAIRS;
    int r = 0, s0 = 0;
    while (p >= s0 + (NFIELDS - 1 - r)) { s0 += NFIELDS - 1 - r; ++r; }
    int c = r + 1 + (p - s0);
    const float* pv = emb + ((size_t)b * NFIELDS + r) * EMBED;
    const float* qv = emb + ((size_t)b * NFIELDS + c) * EMBED;
    float acc = 0.f;
    for (int i = 0; i < EMBED; ++i) {
        const float* kr = kern + ((size_t)i * NPAIRS + p) * EMBED;
        float kpv = 0.f;
        for (int j = 0; j < EMBED; ++j) kpv += kr[j] * pv[j];
        acc += kpv * qv[i];
    }
    out[(size_t)b * NPAIRS + p] = acc;
}

extern "C" void kernel_launch(void* const* d_in, const int* in_sizes, int n_in,
                              void* d_out, int out_size, void* d_ws, size_t ws_size,
                              hipStream_t stream) {
    const float* emb  = (const float*)d_in[0];   // (2048, 32, 64) fp32
    const float* kern = (const float*)d_in[1];   // (64, 496, 64) fp32
    float* out = (float*)d_out;                  // (2048, 1, 496) fp32

    if (ws_size >= (size_t)WS_BYTES) {
        unsigned short* ws = (unsigned short*)d_ws;
        float* outT = (float*)((char*)d_ws + OT_OFF_BYTES);
        const int NEMB8 = BATCH * NFIELDS * EMBED / 8;
        const int NKER8 = EMBED * NPAIRS * EMBED / 8;
        int total = NEMB8 + NKER8;
        prepass<<<(total + 255) / 256, 256, 0, stream>>>(emb, kern, ws);
        opn_main<<<dim3(NPG * NBT), 256, 0, stream>>>(ws, outT);
        transpose_out<<<dim3(16, 64), 256, 0, stream>>>(outT, out);
    } else {
        int total = BATCH * NPAIRS;
        opn_naive<<<(total + 255) / 256, 256, 0, stream>>>(emb, kern, out);
    }
}